// Round 2
// baseline (206.348 us; speedup 1.0000x reference)
//
#include <hip/hip_runtime.h>

// out[b][j] = sum_i spikes[b][i] * W[i][j]
//   spikes [8,8192] f32, W [8192,8192] f32 row-major, out [8,8192] f32.
// Memory-bound (4 FLOP/byte): stream 256 MiB of W once at max BW.
// R1: 86us = 3.1 TB/s. Theory: per-iter issue cost (8x ds_read_b32 + 16 FMA
//     per 512B of W) capped us at ~half the HBM roofline.
// R2 changes: float4 W loads (16B/lane), k-major LDS (2x ds_read_b128
//     broadcast per k), KCHUNK=64 split-K with atomics into zeroed out.

constexpr int N_PREV = 8192;
constexpr int N_HID  = 8192;
constexpr int BATCH  = 8;
constexpr int KCHUNK = 64;
constexpr int TPB    = 256;
constexpr int CPT    = 4;                    // cols per thread (float4)
constexpr int COLS_PER_BLOCK = TPB * CPT;    // 1024

__global__ __launch_bounds__(TPB) void snn_gemm_splitk(
    const float* __restrict__ spikes,
    const float* __restrict__ W,
    float* __restrict__ out) {
  __shared__ float s_sp[KCHUNK][BATCH];      // k-major: 8 floats contiguous per k

  const int cb = blockIdx.x;                 // column-block
  const int kc = blockIdx.y;                 // k-chunk
  const int k0 = kc * KCHUNK;
  const int col = cb * COLS_PER_BLOCK + threadIdx.x * CPT;

  // Stage spikes chunk transposed: s_sp[k][b]. 512 elems, 2 per thread.
  for (int t = threadIdx.x; t < KCHUNK * BATCH; t += TPB) {
    const int k = t >> 3;
    const int b = t & 7;
    s_sp[k][b] = spikes[b * N_PREV + k0 + k];
  }
  __syncthreads();

  float acc[BATCH][CPT];
  #pragma unroll
  for (int b = 0; b < BATCH; ++b)
    #pragma unroll
    for (int c = 0; c < CPT; ++c) acc[b][c] = 0.f;

  const float* wp = W + (size_t)k0 * N_HID + col;
  #pragma unroll 4
  for (int k = 0; k < KCHUNK; ++k) {
    const float4 w = *reinterpret_cast<const float4*>(wp);
    wp += N_HID;
    float s_k[BATCH];
    *reinterpret_cast<float4*>(&s_k[0]) =
        *reinterpret_cast<const float4*>(&s_sp[k][0]);   // ds_read_b128 bcast
    *reinterpret_cast<float4*>(&s_k[4]) =
        *reinterpret_cast<const float4*>(&s_sp[k][4]);   // ds_read_b128 bcast
    #pragma unroll
    for (int b = 0; b < BATCH; ++b) {
      acc[b][0] += s_k[b] * w.x;
      acc[b][1] += s_k[b] * w.y;
      acc[b][2] += s_k[b] * w.z;
      acc[b][3] += s_k[b] * w.w;
    }
  }

  #pragma unroll
  for (int b = 0; b < BATCH; ++b)
    #pragma unroll
    for (int c = 0; c < CPT; ++c)
      atomicAdd(&out[b * N_HID + col + c], acc[b][c]);
}

extern "C" void kernel_launch(void* const* d_in, const int* in_sizes, int n_in,
                              void* d_out, int out_size, void* d_ws, size_t ws_size,
                              hipStream_t stream) {
  const float* spikes = (const float*)d_in[0];   // [8, 8192]
  const float* W      = (const float*)d_in[1];   // [8192, 8192]
  float* out          = (float*)d_out;           // [8, 8192]

  // Atomics accumulate -> zero output each call (graph-capturable async memset).
  hipMemsetAsync(out, 0, (size_t)out_size * sizeof(float), stream);

  dim3 grid(N_HID / COLS_PER_BLOCK, N_PREV / KCHUNK);   // (8, 128) = 1024 blocks
  dim3 block(TPB);
  snn_gemm_splitk<<<grid, block, 0, stream>>>(spikes, W, out);
}

// Round 3
// 202.776 us; speedup vs baseline: 1.0176x; 1.0176x over previous
//
#include <hip/hip_runtime.h>

// out[b][j] = sum_i spikes[b][i] * W[i][j]
//   spikes [8,8192] f32, W [8192,8192] f32 row-major, out [8,8192] f32.
// Memory-bound (4 FLOP/byte): stream 256 MiB of W once at max BW.
// R1 (float2, 8x ds_read_b32): 86us = 3.1 TB/s effective.
// R2 (float4 + local-array punning): 206us REGRESSION. VGPR=36, WRITE=128MiB,
//     VALUBusy 3.6% -> type-punned float s_k[8] defeated SROA; acc+s_k spilled
//     to scratch. Lesson: keep loop state in vector-typed registers.
// R3: float4 acc[8] constant-indexed, LDS reads straight into float4 regs.

constexpr int N_PREV = 8192;
constexpr int N_HID  = 8192;
constexpr int BATCH  = 8;
constexpr int KCHUNK = 64;
constexpr int TPB    = 256;
constexpr int CPT    = 4;                    // cols per thread (float4)
constexpr int COLS_PER_BLOCK = TPB * CPT;    // 1024

__global__ __launch_bounds__(TPB) void snn_gemm_splitk(
    const float* __restrict__ spikes,
    const float* __restrict__ W,
    float* __restrict__ out) {
  __shared__ float s_sp[KCHUNK][BATCH];      // k-major: 8 floats contiguous per k

  const int cb = blockIdx.x;                 // column-block
  const int kc = blockIdx.y;                 // k-chunk
  const int k0 = kc * KCHUNK;
  const int col = cb * COLS_PER_BLOCK + threadIdx.x * CPT;

  // Stage spikes chunk transposed: s_sp[k][b]. 512 elems, 2 per thread.
  // Thread t writes byte t*4 -> bank stride 1, conflict-free.
  for (int t = threadIdx.x; t < KCHUNK * BATCH; t += TPB) {
    const int k = t >> 3;
    const int b = t & 7;
    s_sp[k][b] = spikes[b * N_PREV + k0 + k];
  }
  __syncthreads();

  float4 acc[BATCH];                         // 32 VGPRs, all constant-indexed
  #pragma unroll
  for (int b = 0; b < BATCH; ++b) acc[b] = make_float4(0.f, 0.f, 0.f, 0.f);

  const float* wp = W + (size_t)k0 * N_HID + col;
  #pragma unroll 4
  for (int k = 0; k < KCHUNK; ++k) {
    const float4 w = *reinterpret_cast<const float4*>(wp);
    wp += N_HID;
    const float4 slo = *reinterpret_cast<const float4*>(&s_sp[k][0]); // bcast b128
    const float4 shi = *reinterpret_cast<const float4*>(&s_sp[k][4]); // bcast b128
    acc[0].x += slo.x * w.x; acc[0].y += slo.x * w.y; acc[0].z += slo.x * w.z; acc[0].w += slo.x * w.w;
    acc[1].x += slo.y * w.x; acc[1].y += slo.y * w.y; acc[1].z += slo.y * w.z; acc[1].w += slo.y * w.w;
    acc[2].x += slo.z * w.x; acc[2].y += slo.z * w.y; acc[2].z += slo.z * w.z; acc[2].w += slo.z * w.w;
    acc[3].x += slo.w * w.x; acc[3].y += slo.w * w.y; acc[3].z += slo.w * w.z; acc[3].w += slo.w * w.w;
    acc[4].x += shi.x * w.x; acc[4].y += shi.x * w.y; acc[4].z += shi.x * w.z; acc[4].w += shi.x * w.w;
    acc[5].x += shi.y * w.x; acc[5].y += shi.y * w.y; acc[5].z += shi.y * w.z; acc[5].w += shi.y * w.w;
    acc[6].x += shi.z * w.x; acc[6].y += shi.z * w.y; acc[6].z += shi.z * w.z; acc[6].w += shi.z * w.w;
    acc[7].x += shi.w * w.x; acc[7].y += shi.w * w.y; acc[7].z += shi.w * w.z; acc[7].w += shi.w * w.w;
  }

  #pragma unroll
  for (int b = 0; b < BATCH; ++b) {
    float* op = &out[b * N_HID + col];
    atomicAdd(op + 0, acc[b].x);
    atomicAdd(op + 1, acc[b].y);
    atomicAdd(op + 2, acc[b].z);
    atomicAdd(op + 3, acc[b].w);
  }
}

extern "C" void kernel_launch(void* const* d_in, const int* in_sizes, int n_in,
                              void* d_out, int out_size, void* d_ws, size_t ws_size,
                              hipStream_t stream) {
  const float* spikes = (const float*)d_in[0];   // [8, 8192]
  const float* W      = (const float*)d_in[1];   // [8192, 8192]
  float* out          = (float*)d_out;           // [8, 8192]

  // Atomics accumulate -> zero output each call (graph-capturable async memset).
  hipMemsetAsync(out, 0, (size_t)out_size * sizeof(float), stream);

  dim3 grid(N_HID / COLS_PER_BLOCK, N_PREV / KCHUNK);   // (8, 128) = 1024 blocks
  dim3 block(TPB);
  snn_gemm_splitk<<<grid, block, 0, stream>>>(spikes, W, out);
}

// Round 4
// 58.523 us; speedup vs baseline: 3.5259x; 3.4649x over previous
//
#include <hip/hip_runtime.h>

// out[b][j] = sum_i spikes[b][i] * W[i][j]
//   spikes [8,8192] f32, W [8192,8192] f32 row-major, out [8,8192] f32.
// History:
//  R1 (float2, 8x ds_read_b32, 4.2M atomics): 86us.
//  R2/R3 (float4, acc array): 202-206us. VGPR=36 -> float4 acc[8] ARRAY was
//    demoted to scratch (rule #20); ~2400cy/iter serialized scratch RMW.
//    WRITE=134MB = 8.4M atomics x 16B memory-side RMW (second ceiling).
//  R4: (a) NAMED float4 accumulators a0..a7 — no private arrays at all;
//      (b) no atomics: stage-1 writes split-K partials (16.8MB) to d_ws,
//          stage-2 reduces 64 slabs -> out. Atomic fallback if ws too small.

constexpr int N_PREV = 8192;
constexpr int N_HID  = 8192;
constexpr int BATCH  = 8;
constexpr int TPB    = 256;
constexpr int CPT    = 4;                      // cols per thread (float4)
constexpr int COLS_PER_BLOCK = TPB * CPT;      // 1024
constexpr int KCHUNK = 128;
constexpr int NKC    = N_PREV / KCHUNK;        // 64 k-chunks
constexpr int OUT_ELEMS = BATCH * N_HID;       // 65536

#define FMA4(A, S) \
  A.x += (S) * w.x; A.y += (S) * w.y; A.z += (S) * w.z; A.w += (S) * w.w;

template <bool USE_ATOMIC>
__global__ __launch_bounds__(TPB) void snn_stage1(
    const float* __restrict__ spikes,
    const float* __restrict__ W,
    float* __restrict__ dst) {        // partial buffer, or out if USE_ATOMIC
  __shared__ float s_sp[KCHUNK][BATCH];        // k-major spikes chunk

  const int cb  = blockIdx.x;
  const int p   = blockIdx.y;                  // k-chunk index
  const int k0  = p * KCHUNK;
  const int col = cb * COLS_PER_BLOCK + threadIdx.x * CPT;

  // Stage spikes chunk transposed; thread t writes float #t -> conflict-free.
  for (int t = threadIdx.x; t < KCHUNK * BATCH; t += TPB) {
    const int k = t >> 3, b = t & 7;
    s_sp[k][b] = spikes[b * N_PREV + k0 + k];
  }
  __syncthreads();

  // Named accumulators: guaranteed VGPRs (no private arrays anywhere).
  float4 a0 = {0,0,0,0}, a1 = {0,0,0,0}, a2 = {0,0,0,0}, a3 = {0,0,0,0};
  float4 a4 = {0,0,0,0}, a5 = {0,0,0,0}, a6 = {0,0,0,0}, a7 = {0,0,0,0};

  const float* wp = W + (size_t)k0 * N_HID + col;
  #pragma unroll 8
  for (int k = 0; k < KCHUNK; ++k) {
    const float4 w = *reinterpret_cast<const float4*>(wp);
    wp += N_HID;
    const float4 slo = *reinterpret_cast<const float4*>(&s_sp[k][0]); // b128 bcast
    const float4 shi = *reinterpret_cast<const float4*>(&s_sp[k][4]); // b128 bcast
    FMA4(a0, slo.x) FMA4(a1, slo.y) FMA4(a2, slo.z) FMA4(a3, slo.w)
    FMA4(a4, shi.x) FMA4(a5, shi.y) FMA4(a6, shi.z) FMA4(a7, shi.w)
  }

  if constexpr (USE_ATOMIC) {
    #define EMIT(b, A) { float* op = &dst[(b) * N_HID + col]; \
      atomicAdd(op+0, A.x); atomicAdd(op+1, A.y);             \
      atomicAdd(op+2, A.z); atomicAdd(op+3, A.w); }
    EMIT(0, a0) EMIT(1, a1) EMIT(2, a2) EMIT(3, a3)
    EMIT(4, a4) EMIT(5, a5) EMIT(6, a6) EMIT(7, a7)
    #undef EMIT
  } else {
    float* base = dst + (size_t)p * OUT_ELEMS + col;
    #define EMIT(b, A) *reinterpret_cast<float4*>(base + (b) * N_HID) = A;
    EMIT(0, a0) EMIT(1, a1) EMIT(2, a2) EMIT(3, a3)
    EMIT(4, a4) EMIT(5, a5) EMIT(6, a6) EMIT(7, a7)
    #undef EMIT
  }
}

// out[j] = sum_p partial[p][j], one float4 per thread. 16384 float4s.
__global__ __launch_bounds__(TPB) void snn_stage2(
    const float* __restrict__ partial, float* __restrict__ out) {
  const int j4 = blockIdx.x * TPB + threadIdx.x;     // 0..16383
  const float4* p4 = reinterpret_cast<const float4*>(partial) + j4;
  float4 s = {0,0,0,0};
  #pragma unroll 8
  for (int p = 0; p < NKC; ++p) {
    const float4 v = p4[(size_t)p * (OUT_ELEMS / 4)];
    s.x += v.x; s.y += v.y; s.z += v.z; s.w += v.w;
  }
  reinterpret_cast<float4*>(out)[j4] = s;
}

extern "C" void kernel_launch(void* const* d_in, const int* in_sizes, int n_in,
                              void* d_out, int out_size, void* d_ws, size_t ws_size,
                              hipStream_t stream) {
  const float* spikes = (const float*)d_in[0];   // [8, 8192]
  const float* W      = (const float*)d_in[1];   // [8192, 8192]
  float* out          = (float*)d_out;           // [8, 8192]
  float* partial      = (float*)d_ws;

  const size_t need = (size_t)NKC * OUT_ELEMS * sizeof(float);  // 16.8 MB
  dim3 grid(N_HID / COLS_PER_BLOCK, NKC);        // (8, 64) = 512 blocks
  dim3 block(TPB);

  if (ws_size >= need) {
    snn_stage1<false><<<grid, block, 0, stream>>>(spikes, W, partial);
    snn_stage2<<<dim3(OUT_ELEMS / 4 / TPB), block, 0, stream>>>(partial, out);
  } else {
    // Fallback: atomics into zeroed out (deterministic host-side branch).
    hipMemsetAsync(out, 0, (size_t)out_size * sizeof(float), stream);
    snn_stage1<true><<<grid, block, 0, stream>>>(spikes, W, out);
  }
}

// Round 5
// 58.244 us; speedup vs baseline: 3.5428x; 1.0048x over previous
//
#include <hip/hip_runtime.h>

// out[b][j] = sum_i spikes[b][i] * W[i][j]
//   spikes [8,8192] f32, W [8192,8192] f32 row-major, out [8,8192] f32.
// History:
//  R1 (float2, 8x ds_read_b32, 4.2M atomics): 86us.
//  R2/R3 (float4, acc ARRAY): 202-206us — array demoted to scratch (VGPR=36),
//    plus 8.4M atomicAdds = 134MB of memory-side RMW. Two ceilings at once.
//  R4 (named float4 accs a0..a7 + two-stage split-K, no atomics): 58.5us.
//    Stage-1 back-solves to ~6.0 TB/s (~95% of the 6.8 TB/s the harness's own
//    1GiB fills achieve). Stage-2 used only 64 blocks -> ~11us, machine 3/4 idle.
//  R5: stage-2 re-gridded to 256 blocks x 64 threads (full-width reduction).

constexpr int N_PREV = 8192;
constexpr int N_HID  = 8192;
constexpr int BATCH  = 8;
constexpr int TPB    = 256;
constexpr int CPT    = 4;                      // cols per thread (float4)
constexpr int COLS_PER_BLOCK = TPB * CPT;      // 1024
constexpr int KCHUNK = 128;
constexpr int NKC    = N_PREV / KCHUNK;        // 64 k-chunks
constexpr int OUT_ELEMS = BATCH * N_HID;       // 65536

#define FMA4(A, S) \
  A.x += (S) * w.x; A.y += (S) * w.y; A.z += (S) * w.z; A.w += (S) * w.w;

template <bool USE_ATOMIC>
__global__ __launch_bounds__(TPB) void snn_stage1(
    const float* __restrict__ spikes,
    const float* __restrict__ W,
    float* __restrict__ dst) {        // partial buffer, or out if USE_ATOMIC
  __shared__ float s_sp[KCHUNK][BATCH];        // k-major spikes chunk

  const int cb  = blockIdx.x;
  const int p   = blockIdx.y;                  // k-chunk index
  const int k0  = p * KCHUNK;
  const int col = cb * COLS_PER_BLOCK + threadIdx.x * CPT;

  // Stage spikes chunk transposed; thread t writes float #t -> conflict-free.
  for (int t = threadIdx.x; t < KCHUNK * BATCH; t += TPB) {
    const int k = t >> 3, b = t & 7;
    s_sp[k][b] = spikes[b * N_PREV + k0 + k];
  }
  __syncthreads();

  // Named accumulators: guaranteed VGPRs (no private arrays anywhere).
  float4 a0 = {0,0,0,0}, a1 = {0,0,0,0}, a2 = {0,0,0,0}, a3 = {0,0,0,0};
  float4 a4 = {0,0,0,0}, a5 = {0,0,0,0}, a6 = {0,0,0,0}, a7 = {0,0,0,0};

  const float* wp = W + (size_t)k0 * N_HID + col;
  #pragma unroll 8
  for (int k = 0; k < KCHUNK; ++k) {
    const float4 w = *reinterpret_cast<const float4*>(wp);
    wp += N_HID;
    const float4 slo = *reinterpret_cast<const float4*>(&s_sp[k][0]); // b128 bcast
    const float4 shi = *reinterpret_cast<const float4*>(&s_sp[k][4]); // b128 bcast
    FMA4(a0, slo.x) FMA4(a1, slo.y) FMA4(a2, slo.z) FMA4(a3, slo.w)
    FMA4(a4, shi.x) FMA4(a5, shi.y) FMA4(a6, shi.z) FMA4(a7, shi.w)
  }

  if constexpr (USE_ATOMIC) {
    #define EMIT(b, A) { float* op = &dst[(b) * N_HID + col]; \
      atomicAdd(op+0, A.x); atomicAdd(op+1, A.y);             \
      atomicAdd(op+2, A.z); atomicAdd(op+3, A.w); }
    EMIT(0, a0) EMIT(1, a1) EMIT(2, a2) EMIT(3, a3)
    EMIT(4, a4) EMIT(5, a5) EMIT(6, a6) EMIT(7, a7)
    #undef EMIT
  } else {
    float* base = dst + (size_t)p * OUT_ELEMS + col;
    #define EMIT(b, A) *reinterpret_cast<float4*>(base + (b) * N_HID) = A;
    EMIT(0, a0) EMIT(1, a1) EMIT(2, a2) EMIT(3, a3)
    EMIT(4, a4) EMIT(5, a5) EMIT(6, a6) EMIT(7, a7)
    #undef EMIT
  }
}

// out[j4] = sum_p partial[p][j4]. One float4 per thread.
// 256 blocks x 64 threads = full-machine width; 64 independent 16B loads per
// thread (consecutive lanes -> 1KiB contiguous per slab step).
constexpr int TPB2 = 64;

__global__ __launch_bounds__(TPB2) void snn_stage2(
    const float* __restrict__ partial, float* __restrict__ out) {
  const int j4 = blockIdx.x * TPB2 + threadIdx.x;    // 0..16383
  const float4* p4 = reinterpret_cast<const float4*>(partial) + j4;
  float4 s = {0,0,0,0};
  #pragma unroll 8
  for (int p = 0; p < NKC; ++p) {
    const float4 v = p4[(size_t)p * (OUT_ELEMS / 4)];
    s.x += v.x; s.y += v.y; s.z += v.z; s.w += v.w;
  }
  reinterpret_cast<float4*>(out)[j4] = s;
}

extern "C" void kernel_launch(void* const* d_in, const int* in_sizes, int n_in,
                              void* d_out, int out_size, void* d_ws, size_t ws_size,
                              hipStream_t stream) {
  const float* spikes = (const float*)d_in[0];   // [8, 8192]
  const float* W      = (const float*)d_in[1];   // [8192, 8192]
  float* out          = (float*)d_out;           // [8, 8192]
  float* partial      = (float*)d_ws;

  const size_t need = (size_t)NKC * OUT_ELEMS * sizeof(float);  // 16.8 MB
  dim3 grid(N_HID / COLS_PER_BLOCK, NKC);        // (8, 64) = 512 blocks
  dim3 block(TPB);

  if (ws_size >= need) {
    snn_stage1<false><<<grid, block, 0, stream>>>(spikes, W, partial);
    snn_stage2<<<dim3(OUT_ELEMS / 4 / TPB2), dim3(TPB2), 0, stream>>>(partial, out);
  } else {
    // Fallback: atomics into zeroed out (deterministic host-side branch).
    hipMemsetAsync(out, 0, (size_t)out_size * sizeof(float), stream);
    snn_stage1<true><<<grid, block, 0, stream>>>(spikes, W, out);
  }
}